// Round 9
// baseline (48.893 us; speedup 1.0000x reference)
//
#include <hip/hip_runtime.h>
#include <stdint.h>

#define INPUT_SCALE 0.0078125f   // 2^-7

typedef __attribute__((ext_vector_type(4))) unsigned int u32x4;

__device__ __forceinline__ uint32_t sadu8(uint32_t a, uint32_t b, uint32_t c) {
#if __has_builtin(__builtin_amdgcn_sad_u8)
    return __builtin_amdgcn_sad_u8(a, b, c);
#else
    uint32_t d;
    asm("v_sad_u8 %0, %1, %2, %3" : "=v"(d) : "v"(a), "v"(b), "v"(c));
    return d;
#endif
}

__device__ __forceinline__ uint32_t qbyte(float x) {
    // round(clip(x*128, -127, 127)) + 128  (rintf = round-half-even, matches jnp.round)
    float v = fminf(fmaxf(x * 128.0f, -127.0f), 127.0f);
    return (uint32_t)((int)rintf(v) + 128);
}

// ---------------- Kernel A: weight scale + quantize + pack ----------------
// qwp layout: u = (f*9 + kpos)*8 + cg ; byte b of u32 = channel 4*cg+b, kpos = kh*3+kw
__global__ __launch_bounds__(1024) void quant_weight(const float* __restrict__ w,
                                                     uint32_t* __restrict__ qwp) {
    __shared__ float red[1024];
    __shared__ float s_inv;
    int tid = threadIdx.x;
    float m = 0.0f;
    for (int i = tid; i < 9216; i += 1024) m = fmaxf(m, fabsf(w[i]));
    red[tid] = m;
    __syncthreads();
    for (int s = 512; s > 0; s >>= 1) {
        if (tid < s) red[tid] = fmaxf(red[tid], red[tid + s]);
        __syncthreads();
    }
    if (tid == 0) {
        float s = fmaxf(red[0] / 127.0f, 1e-8f);
        int e; float fr = frexpf(s, &e);            // s = fr * 2^e, fr in [0.5,1)
        int k = (fr >= 0.70710678118654752f) ? e : e - 1;  // round(log2(s))
        s_inv = exp2f((float)(-k));                 // 1/s_w, exact power of 2
    }
    __syncthreads();
    float inv = s_inv;
    for (int u = tid; u < 2304; u += 1024) {
        int f = u / 72, rem = u % 72, kpos = rem / 8, cg = rem % 8;
        int kh = kpos / 3, kw = kpos % 3;
        uint32_t pk = 0;
        #pragma unroll
        for (int b = 0; b < 4; ++b) {
            int c = cg * 4 + b;
            float v = w[((f * 32 + c) * 3 + kh) * 3 + kw] * inv;
            v = fminf(fmaxf(v, -127.0f), 127.0f);
            pk |= ((uint32_t)((int)rintf(v) + 128) & 0xFFu) << (8 * b);
        }
        qwp[u] = pk;
    }
}

// ---------------- Kernel B: fused quantize + SAD conv ----------------
// Identical to R8 except amdgpu_waves_per_eu(4,4): launch_bounds' 2nd arg is a
// MINIMUM — the allocator over-squeezed to 40 arch-VGPRs (demoting the pinned
// window to AGPRs / extra moves, VALU issue 1.9x ideal). Pinning max waves = 4
// gives it the full 128-VGPR budget with no occupancy incentive to demote.
#define LSTRIDE 12  // u32 per pixel slot (32B data + 16B pad)
__global__ __launch_bounds__(512)
__attribute__((amdgpu_waves_per_eu(4, 4)))
void adder_conv_fused(const float* __restrict__ x,
                      const uint32_t* __restrict__ qwp,
                      float* __restrict__ out) {
    __shared__ __align__(16) uint32_t sx[18 * 34 * LSTRIDE];  // 29376 B
    int tid = threadIdx.x;
    int b = blockIdx.x;
    int n = b >> 5;
    int rem = b & 31;
    int h0 = (rem >> 2) * 16, w0 = (rem & 3) * 32;

    // quantize + pack the 18x34 halo (32 ch -> 8 u32/pixel) into LDS.
    for (int q = tid; q < 4896; q += 512) {          // 4896 = 612 px * 8 cg
        int cg = q / 612;
        int pixel = q - cg * 612;
        int r = pixel / 34, cc = pixel - r * 34;
        int gh = h0 - 1 + r, gw = w0 - 1 + cc;
        uint32_t pk = 0x80808080u;                   // quantized-zero padding
        if ((unsigned)gh < 128u && (unsigned)gw < 128u) {
            const float* base = x + (((size_t)n * 32 + cg * 4) * 128 + gh) * 128 + gw;
            pk = qbyte(base[0])
               | (qbyte(base[16384]) << 8)
               | (qbyte(base[32768]) << 16)
               | (qbyte(base[49152]) << 24);
        }
        sx[pixel * LSTRIDE + cg] = pk;
    }
    __syncthreads();

    int c = tid & 31;    // col in tile
    int r = tid >> 5;    // row in tile 0..15

    // byte address of this thread's (r, c) halo corner in LDS
    uint32_t laddr = (uint32_t)(uintptr_t)(&sx[(r * 34 + c) * LSTRIDE]);

    u32x4 nb[3][3][2];   // 18 uint4 = 72 VGPRs, pinned by volatile asm
    #define LOADPX(dr, dc, i)                                                      \
        asm volatile("ds_read_b128 %0, %1 offset:%2"                               \
                     : "=v"(nb[dr][dc][i])                                         \
                     : "v"(laddr), "i"((((dr) * 34 + (dc)) * LSTRIDE + (i) * 4) * 4))
    LOADPX(0, 0, 0); LOADPX(0, 0, 1);
    LOADPX(0, 1, 0); LOADPX(0, 1, 1);
    LOADPX(0, 2, 0); LOADPX(0, 2, 1);
    LOADPX(1, 0, 0); LOADPX(1, 0, 1);
    LOADPX(1, 1, 0); LOADPX(1, 1, 1);
    LOADPX(1, 2, 0); LOADPX(1, 2, 1);
    LOADPX(2, 0, 0); LOADPX(2, 0, 1);
    LOADPX(2, 1, 0); LOADPX(2, 1, 1);
    LOADPX(2, 2, 0); LOADPX(2, 2, 1);
    #undef LOADPX
    asm volatile("s_waitcnt lgkmcnt(0)" ::: "memory");
    __builtin_amdgcn_sched_barrier(0);   // nothing crosses the wait (rule #18)

    size_t obase = ((size_t)(n * 32) * 128 + (h0 + r)) * 128 + (w0 + c);
    #pragma unroll 1
    for (int f = 0; f < 32; ++f) {
        const uint32_t* wf = qwp + f * 72;   // uniform -> s_load via K$
        uint32_t s0 = 0, s1 = 0, s2 = 0, s3 = 0;   // 4 independent sad chains
        #pragma unroll
        for (int t = 0; t < 9; ++t) {
            int kh = t / 3, kw = t - kh * 3;
            const uint4* wp = (const uint4*)(wf + t * 8);
            uint4 wv0 = wp[0], wv1 = wp[1];
            u32x4 x0 = nb[kh][kw][0], x1 = nb[kh][kw][1];
            s0 = sadu8(x0.x, wv0.x, s0);
            s1 = sadu8(x0.y, wv0.y, s1);
            s2 = sadu8(x0.z, wv0.z, s2);
            s3 = sadu8(x0.w, wv0.w, s3);
            s0 = sadu8(x1.x, wv1.x, s0);
            s1 = sadu8(x1.y, wv1.y, s1);
            s2 = sadu8(x1.z, wv1.z, s2);
            s3 = sadu8(x1.w, wv1.w, s3);
        }
        out[obase + (size_t)f * 16384] = -(float)((s0 + s1) + (s2 + s3)) * INPUT_SCALE;
    }
}

extern "C" void kernel_launch(void* const* d_in, const int* in_sizes, int n_in,
                              void* d_out, int out_size, void* d_ws, size_t ws_size,
                              hipStream_t stream) {
    const float* x = (const float*)d_in[0];       // (16,32,128,128)
    const float* w = (const float*)d_in[1];       // (32,32,3,3)
    float* out = (float*)d_out;                   // (16,32,128,128)

    uint32_t* qwp = (uint32_t*)d_ws;              // 9216 B

    quant_weight<<<1, 1024, 0, stream>>>(w, qwp);
    adder_conv_fused<<<512, 512, 0, stream>>>(x, qwp, out);
}

// Round 11
// 39.809 us; speedup vs baseline: 1.2282x; 1.2282x over previous
//
#include <hip/hip_runtime.h>
#include <stdint.h>

#define INPUT_SCALE 0.0078125f   // 2^-7

__device__ __forceinline__ uint32_t sadu8(uint32_t a, uint32_t b, uint32_t c) {
#if __has_builtin(__builtin_amdgcn_sad_u8)
    return __builtin_amdgcn_sad_u8(a, b, c);
#else
    uint32_t d;
    asm("v_sad_u8 %0, %1, %2, %3" : "=v"(d) : "v"(a), "v"(b), "v"(c));
    return d;
#endif
}

__device__ __forceinline__ uint32_t qbyte(float x) {
    // round(clip(x*128, -127, 127)) + 128  (rintf = round-half-even, matches jnp.round)
    float v = fminf(fmaxf(x * 128.0f, -127.0f), 127.0f);
    return (uint32_t)((int)rintf(v) + 128);
}

// ---------------- Kernel A: weight scale + quantize + pack ----------------
// Tap-major layout: u = (t*32 + f)*8 + cg, t = kh*3+kw.
// One tap's 32 filters = 1 KB contiguous -> s_load_dwordx16 runs in kernel B.
__global__ __launch_bounds__(1024) void quant_weight(const float* __restrict__ w,
                                                     uint32_t* __restrict__ qwp) {
    __shared__ float red[1024];
    __shared__ float s_inv;
    int tid = threadIdx.x;
    float m = 0.0f;
    for (int i = tid; i < 9216; i += 1024) m = fmaxf(m, fabsf(w[i]));
    red[tid] = m;
    __syncthreads();
    for (int s = 512; s > 0; s >>= 1) {
        if (tid < s) red[tid] = fmaxf(red[tid], red[tid + s]);
        __syncthreads();
    }
    if (tid == 0) {
        float s = fmaxf(red[0] / 127.0f, 1e-8f);
        int e; float fr = frexpf(s, &e);            // s = fr * 2^e, fr in [0.5,1)
        int k = (fr >= 0.70710678118654752f) ? e : e - 1;  // round(log2(s))
        s_inv = exp2f((float)(-k));                 // 1/s_w, exact power of 2
    }
    __syncthreads();
    float inv = s_inv;
    for (int u = tid; u < 2304; u += 1024) {
        int t = u >> 8;            // tap 0..8
        int rem = u & 255;
        int f = rem >> 3, cg = rem & 7;
        int kh = t / 3, kw = t - kh * 3;
        uint32_t pk = 0;
        #pragma unroll
        for (int b = 0; b < 4; ++b) {
            int c = cg * 4 + b;
            float v = w[((f * 32 + c) * 3 + kh) * 3 + kw] * inv;
            v = fminf(fmaxf(v, -127.0f), 127.0f);
            pk |= ((uint32_t)((int)rintf(v) + 128) & 0xFFu) << (8 * b);
        }
        qwp[u] = pk;
    }
}

// ---------------- Kernel B: fused quantize + SAD conv ----------------
// Tile 32x8. 512 threads = 256 px x 2 filter-halves (F=16 each).
// Grid 1024 (= 16 images x 64 tiles; R10 launched 2048 -> n OOB -> segfault).
// 4 blocks/CU x 8 waves = 32 waves/CU — SMEM latency hidden by TLP.
// NO long-lived register window (R3/R8/R9: big windows get demoted to AGPRs,
// +1 v_accvgpr_read per use = 2x VALU). Per tap: 2 transient ds_read_b128 +
// fully-unrolled 16 filters with s_load weights (tap-major -> contiguous 512 B
// per (tap,fh)). acc[16] statically indexed = only persistent array.
#define LSTRIDE 12  // u32 per pixel slot (32B data + 16B pad)
__global__ __launch_bounds__(512, 8) void adder_conv_fused(const float* __restrict__ x,
                                                           const uint32_t* __restrict__ qwp,
                                                           float* __restrict__ out) {
    __shared__ __align__(16) uint32_t sx[10 * 34 * LSTRIDE];  // 16320 B
    int tid = threadIdx.x;
    // XCD-contiguous remap: XCD k owns 128 consecutive tiles (2 images) so
    // halo-overlapping tiles share that XCD's L2. 1024 % 8 == 0 -> bijective.
    int b = ((blockIdx.x & 7) << 7) + (blockIdx.x >> 3);
    int n = b >> 6;                 // image 0..15
    int rem = b & 63;               // tile in image
    int h0 = (rem >> 2) * 8, w0 = (rem & 3) * 32;

    // quantize + pack the 10x34 halo (32 ch -> 8 u32/pixel) into LDS.
    // cg = q/340: lanes sweep consecutive pixels of one channel-group.
    for (int q = tid; q < 2720; q += 512) {          // 2720 = 340 px * 8 cg
        int cg = q / 340;
        int pixel = q - cg * 340;
        int r = pixel / 34, cc = pixel - r * 34;
        int gh = h0 - 1 + r, gw = w0 - 1 + cc;
        uint32_t pk = 0x80808080u;                   // quantized-zero padding
        if ((unsigned)gh < 128u && (unsigned)gw < 128u) {
            const float* base = x + (((size_t)n * 32 + cg * 4) * 128 + gh) * 128 + gw;
            pk = qbyte(base[0])
               | (qbyte(base[16384]) << 8)
               | (qbyte(base[32768]) << 16)
               | (qbyte(base[49152]) << 24);
        }
        sx[pixel * LSTRIDE + cg] = pk;
    }
    __syncthreads();

    int fh = __builtin_amdgcn_readfirstlane(tid >> 8);  // filter half (wave-uniform)
    int px = tid & 255;
    int r = px >> 5;          // row in tile 0..7
    int c = px & 31;          // col in tile

    uint32_t acc[16];
    #pragma unroll
    for (int f = 0; f < 16; ++f) acc[f] = 0u;

    int lbase = (r * 34 + c) * LSTRIDE;
    #pragma unroll 1
    for (int kh = 0; kh < 3; ++kh) {
        #pragma unroll 1
        for (int kw = 0; kw < 3; ++kw) {
            // transient pixel read for this tap (2 ds_read_b128)
            const uint4* p = (const uint4*)(sx + lbase + (kh * 34 + kw) * LSTRIDE);
            uint4 x0 = p[0];
            uint4 x1 = p[1];
            // this tap's 16 filters: contiguous 512 B -> s_load_dwordx16 runs
            const uint32_t* wt = qwp + (((kh * 3 + kw) * 32) + fh * 16) * 8;
            #pragma unroll
            for (int f = 0; f < 16; ++f) {
                const uint4* wp = (const uint4*)(wt + f * 8);
                uint4 wv0 = wp[0], wv1 = wp[1];
                uint32_t a = acc[f];
                a = sadu8(x0.x, wv0.x, a);
                a = sadu8(x0.y, wv0.y, a);
                a = sadu8(x0.z, wv0.z, a);
                a = sadu8(x0.w, wv0.w, a);
                a = sadu8(x1.x, wv1.x, a);
                a = sadu8(x1.y, wv1.y, a);
                a = sadu8(x1.z, wv1.z, a);
                a = sadu8(x1.w, wv1.w, a);
                acc[f] = a;
            }
        }
    }

    size_t obase = (((size_t)n * 32 + fh * 16) * 128 + (h0 + r)) * 128 + (w0 + c);
    #pragma unroll
    for (int f = 0; f < 16; ++f) {
        out[obase + (size_t)f * 16384] = -(float)acc[f] * INPUT_SCALE;
    }
}

extern "C" void kernel_launch(void* const* d_in, const int* in_sizes, int n_in,
                              void* d_out, int out_size, void* d_ws, size_t ws_size,
                              hipStream_t stream) {
    const float* x = (const float*)d_in[0];       // (16,32,128,128)
    const float* w = (const float*)d_in[1];       // (32,32,3,3)
    float* out = (float*)d_out;                   // (16,32,128,128)

    uint32_t* qwp = (uint32_t*)d_ws;              // 9216 B

    quant_weight<<<1, 1024, 0, stream>>>(w, qwp);
    adder_conv_fused<<<1024, 512, 0, stream>>>(x, qwp, out);
}